// Round 6
// baseline (423.224 us; speedup 1.0000x reference)
//
#include <hip/hip_runtime.h>
#include <math.h>

typedef unsigned short u16;
typedef __attribute__((ext_vector_type(8))) short bf16x8;
typedef __attribute__((ext_vector_type(4))) float f32x4;

#define NN 32768      // total nodes
#define EDGES 524288  // total edges
#define NB 64         // graphs
#define NPG 512       // nodes per graph
#define KEEP 256      // kept per graph
#define D 512         // feature dim

__device__ __forceinline__ float b2f(u16 h){ return __uint_as_float(((unsigned)h)<<16); }
__device__ __forceinline__ u16 f2b(float f){
  unsigned u = __float_as_uint(f);
  unsigned r = u + 0x7FFFu + ((u>>16)&1u);   // RNE
  return (u16)(r>>16);
}

// async global->LDS, 16B per lane (dest must be wave-uniform base + lane*16)
__device__ __forceinline__ void gload16(const void* g, void* l){
  __builtin_amdgcn_global_load_lds((const __attribute__((address_space(1))) void*)g,
                                   (__attribute__((address_space(3))) void*)l, 16, 0, 0);
}

// ---------- dtype detection: are float inputs f32 (flag=1) or bf16 (flag=0)? ----------
__global__ __launch_bounds__(256) void detect_kernel(const u16* __restrict__ xb, int* __restrict__ flags){
  __shared__ int cnt;
  if (threadIdx.x==0) cnt = 0;
  __syncthreads();
  u16 v = xb[threadIdx.x];
  int e = (v>>7)&0xFF;
  if (e > 140) atomicAdd(&cnt, 1);
  __syncthreads();
  if (threadIdx.x==0){ flags[0] = (cnt > 8) ? 1 : 0; flags[1] = 1; }
}

__global__ __launch_bounds__(256) void zero3_kernel(int* __restrict__ p){
  p[blockIdx.x*256 + threadIdx.x] = 0;   // covers dego, degi, cursor (3*NN ints)
}

// ---------------- graph preprocessing ----------------

__global__ __launch_bounds__(256) void deg_kernel(const int* __restrict__ src, const int* __restrict__ dst,
                                                  int* __restrict__ dego, int* __restrict__ degi){
  int e = blockIdx.x*256 + threadIdx.x;
  if (e < EDGES){
    atomicAdd(&dego[src[e]], 1);
    atomicAdd(&degi[dst[e]], 1);
  }
}

__global__ __launch_bounds__(256) void norm_kernel(const int* __restrict__ dego, const int* __restrict__ degi,
                                                   float* __restrict__ no, float* __restrict__ ni){
  int v = blockIdx.x*256 + threadIdx.x;
  if (v < NN){
    int a = dego[v]; if (a < 1) a = 1;
    int b = degi[v]; if (b < 1) b = 1;
    no[v] = (float)(1.0/sqrt((double)a));
    ni[v] = (float)(1.0/sqrt((double)b));
  }
}

__global__ __launch_bounds__(1024) void scan_kernel(const int* __restrict__ degi, int* __restrict__ rowp){
  __shared__ int sums[1024];
  int t = threadIdx.x;
  int base = t*32;
  int loc[32];
  int s = 0;
  #pragma unroll
  for (int i=0;i<32;i++){ loc[i] = s; s += degi[base+i]; }
  sums[t] = s;
  __syncthreads();
  for (int off=1; off<1024; off<<=1){
    int v = (t>=off) ? sums[t-off] : 0;
    __syncthreads();
    sums[t] += v;
    __syncthreads();
  }
  int excl = (t==0) ? 0 : sums[t-1];
  #pragma unroll
  for (int i=0;i<32;i++) rowp[base+i] = excl + loc[i];
  if (t==1023) rowp[NN] = sums[1023];
}

__global__ __launch_bounds__(256) void fill_kernel(const int* __restrict__ src, const int* __restrict__ dst,
                                                   const int* __restrict__ rowp, int* __restrict__ cursor,
                                                   int* __restrict__ csr){
  int e = blockIdx.x*256 + threadIdx.x;
  if (e < EDGES){
    int d = dst[e];
    int pos = atomicAdd(&cursor[d], 1);
    csr[rowp[d] + pos] = src[e];
  }
}

// ---------- small-tensor conversion to canonical f32 ----------
__global__ __launch_bounds__(512) void bcvt_kernel(const int* __restrict__ flags,
    const void* b1, const void* b2, const void* sW1, const void* sW2,
    const void* sb1, const void* sb2,
    float* b1c, float* b2c, float* sW1c, float* sW2c, float* sbc)
{
  int t = threadIdx.x;
  int f = flags[0];
  #define CV(p,i) (f ? ((const float*)(p))[i] : b2f(((const u16*)(p))[i]))
  b1c[t]  = CV(b1, t);
  b2c[t]  = CV(b2, t);
  sW1c[t] = CV(sW1, t);
  sW2c[t] = CV(sW2, t);
  if (t==0){ sbc[0] = CV(sb1,0); sbc[1] = CV(sb2,0); }
  #undef CV
}

// ---------- weight transpose + hi/lo bf16 split ----------
__global__ void tsplit_kernel(const int* __restrict__ flags, const void* __restrict__ W,
                              u16* __restrict__ WTh, u16* __restrict__ WTl){
  __shared__ float tile[32][33];
  int f = flags[0];
  int bx = blockIdx.x*32, by = blockIdx.y*32;
  int tx = threadIdx.x, ty = threadIdx.y; // (32,8)
  #pragma unroll
  for (int i=0;i<4;i++){
    size_t idx = (size_t)(by+ty+i*8)*D + bx+tx;
    tile[ty+i*8][tx] = f ? ((const float*)W)[idx] : b2f(((const u16*)W)[idx]);
  }
  __syncthreads();
  #pragma unroll
  for (int i=0;i<4;i++){
    float v = tile[tx][ty+i*8];
    u16 h = f2b(v);
    size_t o = (size_t)(bx+ty+i*8)*D + by+tx;
    WTh[o] = h;
    WTl[o] = f2b(v - b2f(h));
  }
}

// ---------- x split: f32 (or bf16) -> bf16 hi/lo ----------
__global__ __launch_bounds__(256) void xsplit_kernel(const void* __restrict__ X,
    const int* __restrict__ flags, u16* __restrict__ Xh, u16* __restrict__ Xl)
{
  size_t i = ((size_t)blockIdx.x*256 + threadIdx.x)*4;
  float v0,v1,v2,v3;
  if (flags[0]){
    float4 f = *(const float4*)((const float*)X + i);
    v0=f.x; v1=f.y; v2=f.z; v3=f.w;
  } else {
    ushort4 uv = *(const ushort4*)((const u16*)X + i);
    v0=b2f(uv.x); v1=b2f(uv.y); v2=b2f(uv.z); v3=b2f(uv.w);
  }
  ushort4 hh, hl;
  hh.x=f2b(v0); hl.x=f2b(v0-b2f(hh.x));
  hh.y=f2b(v1); hl.y=f2b(v1-b2f(hh.y));
  hh.z=f2b(v2); hl.z=f2b(v2-b2f(hh.z));
  hh.w=f2b(v3); hl.w=f2b(v3-b2f(hh.w));
  *(ushort4*)(Xh+i) = hh;
  *(ushort4*)(Xl+i) = hl;
}

// XCD-pinned block remap for 1024-block GEMM grids: 4 bcol-blocks of one brow -> same XCD
__device__ __forceinline__ void gemm_tile(int id, int& brow, int& bcol){
  int xcd = id & 7, k2 = id >> 3;          // k2: 0..127
  brow = (xcd + 8*(k2 & 31)) * 128;        // 0..255 tiles
  bcol = (k2 >> 5) * 128;                  // 0..3 tiles
}

// ---------------- GEMM: C = (A @ W) * rowscale; A,B pre-split bf16 hi/lo ----------------
// 128x128 tile, BK=32, async global_load_lds staging (m97 two-barrier structure),
// 48 MFMA / K-step (hh + hl + lh products).

__global__ __launch_bounds__(256) void gemm_async(
    const u16* __restrict__ Ahg, const u16* __restrict__ Alg,
    const u16* __restrict__ BTh, const u16* __restrict__ BTl,
    float* __restrict__ C, const float* __restrict__ rowscale)
{
  __shared__ alignas(16) u16 Ah[4][128][8], Alo[4][128][8];
  __shared__ alignas(16) u16 Bh[4][128][8], Bl[4][128][8];
  int t = threadIdx.x;
  int brow, bcol;
  gemm_tile(blockIdx.x, brow, bcol);
  int wid = t>>6, lane = t&63;
  int wm = wid>>1, wn = wid&1;
  f32x4 acc[4][4] = {};
  int q = lane>>4, r = lane&15;

  // staging: chunk c (16B) at LDS byte c*16; thread t owns c=t and c=t+256.
  int crow = t & 127, cq = t >> 7;         // chunk1: q=cq, row=crow; chunk2: q=cq+2
  const u16* pAh = Ahg + (size_t)(brow+crow)*D + cq*8;
  const u16* pAl = Alg + (size_t)(brow+crow)*D + cq*8;
  const u16* pBh = BTh + (size_t)(bcol+crow)*D + cq*8;
  const u16* pBl = BTl + (size_t)(bcol+crow)*D + cq*8;
  u16* lAh = ((u16*)Ah)  + t*8;
  u16* lAl = ((u16*)Alo) + t*8;
  u16* lBh = ((u16*)Bh)  + t*8;
  u16* lBl = ((u16*)Bl)  + t*8;

  for (int kt=0; kt<D; kt+=32){
    __syncthreads();                         // previous frags consumed
    gload16(pAh+kt, lAh);  gload16(pAh+kt+16, lAh+2048);
    gload16(pAl+kt, lAl);  gload16(pAl+kt+16, lAl+2048);
    gload16(pBh+kt, lBh);  gload16(pBh+kt+16, lBh+2048);
    gload16(pBl+kt, lBl);  gload16(pBl+kt+16, lBl+2048);
    __syncthreads();                         // vmcnt(0) drain: tile ready
    bf16x8 fah[4], fal[4], fbh[4], fbl[4];
    #pragma unroll
    for (int m=0;m<4;m++){
      fah[m] = *(const bf16x8*)(&Ah[q][wm*64+m*16+r][0]);
      fal[m] = *(const bf16x8*)(&Alo[q][wm*64+m*16+r][0]);
    }
    #pragma unroll
    for (int n=0;n<4;n++){
      fbh[n] = *(const bf16x8*)(&Bh[q][wn*64+n*16+r][0]);
      fbl[n] = *(const bf16x8*)(&Bl[q][wn*64+n*16+r][0]);
    }
    #pragma unroll
    for (int m=0;m<4;m++)
      #pragma unroll
      for (int n=0;n<4;n++){
        acc[m][n] = __builtin_amdgcn_mfma_f32_16x16x32_bf16(fah[m], fbh[n], acc[m][n], 0,0,0);
        acc[m][n] = __builtin_amdgcn_mfma_f32_16x16x32_bf16(fah[m], fbl[n], acc[m][n], 0,0,0);
        acc[m][n] = __builtin_amdgcn_mfma_f32_16x16x32_bf16(fal[m], fbh[n], acc[m][n], 0,0,0);
      }
  }
  #pragma unroll
  for (int m=0;m<4;m++){
    int rowb = brow + wm*64 + m*16 + q*4;
    #pragma unroll
    for (int n=0;n<4;n++){
      int col = bcol + wn*64 + n*16 + r;
      #pragma unroll
      for (int g=0; g<4; g++){
        int row = rowb + g;
        C[(size_t)row*D + col] = acc[m][n][g] * rowscale[row];
      }
    }
  }
}

// -------- edge aggregation: relu( (sum_{u in N(v)} Y[u]) * ni[v] + b ) --------
// 2 nodes/block, 128 threads/node. CSR row hoisted into lane registers (one coalesced
// load per 64 edges), indices distributed via shfl; gather loop unrolled x4 so 4
// independent L2 accesses stay in flight. XCD-pinned per graph.
// mode 0: write split bf16 hi/lo.  mode 1: write f32 H + fused score dots.

__global__ __launch_bounds__(256) void agg_kernel(
    const float* __restrict__ Y, const int* __restrict__ rowp,
    const int* __restrict__ csr, const float* __restrict__ ni,
    const float* __restrict__ bias, float* __restrict__ H,
    u16* __restrict__ Hh, u16* __restrict__ Hl,
    const float* __restrict__ sW1, const float* __restrict__ sW2,
    float* __restrict__ t1, float* __restrict__ t2, int mode)
{
  int i = blockIdx.x;
  int xcd = i & 7, j = i >> 3;              // j: 0..2047
  int half = threadIdx.x >> 7;              // node within pair
  int t = threadIdx.x & 127;                // float4 chunk
  int lane = threadIdx.x & 63;
  int v = (xcd + 8*(j >> 8))*NPG + ((j & 255)*2 + half);
  int rp0 = rowp[v], rp1 = rowp[v+1];
  const float4* Yv = (const float4*)Y;
  float4 a = {0.f,0.f,0.f,0.f};
  for (int eb = rp0; eb < rp1; eb += 64){
    int cnt = rp1 - eb; if (cnt > 64) cnt = 64;
    int idx = (lane < cnt) ? csr[eb + lane] : 0;
    int e = 0;
    for (; e+4 <= cnt; e += 4){
      int u0 = __shfl(idx, e),   u1 = __shfl(idx, e+1);
      int u2 = __shfl(idx, e+2), u3 = __shfl(idx, e+3);
      float4 y0 = Yv[(size_t)u0*128 + t];
      float4 y1 = Yv[(size_t)u1*128 + t];
      float4 y2 = Yv[(size_t)u2*128 + t];
      float4 y3 = Yv[(size_t)u3*128 + t];
      a.x += (y0.x + y1.x) + (y2.x + y3.x);
      a.y += (y0.y + y1.y) + (y2.y + y3.y);
      a.z += (y0.z + y1.z) + (y2.z + y3.z);
      a.w += (y0.w + y1.w) + (y2.w + y3.w);
    }
    for (; e < cnt; e++){
      int u = __shfl(idx, e);
      float4 y = Yv[(size_t)u*128 + t];
      a.x += y.x; a.y += y.y; a.z += y.z; a.w += y.w;
    }
  }
  float w = ni[v];
  float4 b4 = ((const float4*)bias)[t];
  float4 rr;
  rr.x = fmaxf(a.x*w + b4.x, 0.f);
  rr.y = fmaxf(a.y*w + b4.y, 0.f);
  rr.z = fmaxf(a.z*w + b4.z, 0.f);
  rr.w = fmaxf(a.w*w + b4.w, 0.f);

  if (mode == 0){
    ushort4 hh, hl;
    hh.x = f2b(rr.x); hl.x = f2b(rr.x - b2f(hh.x));
    hh.y = f2b(rr.y); hl.y = f2b(rr.y - b2f(hh.y));
    hh.z = f2b(rr.z); hl.z = f2b(rr.z - b2f(hh.z));
    hh.w = f2b(rr.w); hl.w = f2b(rr.w - b2f(hh.w));
    *(ushort4*)(Hh + (size_t)v*D + t*4) = hh;
    *(ushort4*)(Hl + (size_t)v*D + t*4) = hl;
  } else {
    ((float4*)H)[(size_t)v*128 + t] = rr;
    float4 w1 = ((const float4*)sW1)[t];
    float4 w2 = ((const float4*)sW2)[t];
    float p1 = rr.x*w1.x + rr.y*w1.y + rr.z*w1.z + rr.w*w1.w;
    float p2 = rr.x*w2.x + rr.y*w2.y + rr.z*w2.z + rr.w*w2.w;
    #pragma unroll
    for (int off=32; off>=1; off>>=1){
      p1 += __shfl_xor(p1, off);
      p2 += __shfl_xor(p2, off);
    }
    __shared__ float red1[4], red2[4];
    int wv = threadIdx.x>>6;
    if (lane==0){ red1[wv] = p1; red2[wv] = p2; }
    __syncthreads();
    if (t==0){
      t1[v] = red1[half*2] + red1[half*2+1];
      t2[v] = red2[half*2] + red2[half*2+1];
    }
  }
}

// -------- score aggregation --------

__global__ __launch_bounds__(256) void sagg_kernel(
    const float* __restrict__ t1, const float* __restrict__ t2,
    const int* __restrict__ rowp, const int* __restrict__ csr,
    const float* __restrict__ no, const float* __restrict__ ni,
    const float* __restrict__ sbc, float* __restrict__ score)
{
  int v = blockIdx.x*256 + threadIdx.x;
  if (v >= NN) return;
  double a1 = 0.0, a2 = 0.0;
  int rp1 = rowp[v+1];
  for (int e=rowp[v]; e<rp1; e++){
    int u = csr[e];
    double w = (double)no[u];
    a1 += (double)t1[u]*w;
    a2 += (double)t2[u]*w;
  }
  double wi = (double)ni[v];
  double s1 = a1*wi + (double)sbc[0];
  double s2 = a2*wi + (double)sbc[1];
  score[v] = (float)(0.5*(s1+s2));
}

// -------- per-graph stable top-K via bitonic sort of 512 (score desc, idx asc) --------

__global__ __launch_bounds__(256) void topk_kernel(const float* __restrict__ score,
    int* __restrict__ perm, float* __restrict__ gate)
{
  __shared__ unsigned long long key[NPG];
  int g = blockIdx.x, t = threadIdx.x;
  for (int i=t; i<NPG; i+=256){
    float s = score[g*NPG + i];
    unsigned u = __float_as_uint(s);
    u = (u & 0x80000000u) ? ~u : (u | 0x80000000u);
    unsigned kd = ~u;
    key[i] = ((unsigned long long)kd<<32) | (unsigned)i;
  }
  __syncthreads();
  for (int k=2; k<=NPG; k<<=1){
    for (int j=k>>1; j>0; j>>=1){
      for (int i=t; i<NPG; i+=256){
        int ixj = i ^ j;
        if (ixj > i){
          unsigned long long a = key[i], b = key[ixj];
          bool up = ((i & k) == 0);
          if ((a > b) == up){ key[i] = b; key[ixj] = a; }
        }
      }
      __syncthreads();
    }
  }
  if (t < KEEP){
    unsigned long long e = key[t];
    int idx = (int)(e & 0xFFFFFFFFull);
    int node = g*NPG + idx;
    perm[g*KEEP + t] = node;
    gate[g*KEEP + t] = tanhf(score[node]);
  }
}

// -------- gated gather + readout (f32 outputs) --------

__global__ __launch_bounds__(128) void pooled_kernel(const float* __restrict__ H,
    const int* __restrict__ perm, const float* __restrict__ gate, float* __restrict__ out)
{
  int i = blockIdx.x;
  int xcd = i & 7, j = i >> 3;
  int row = (xcd + 8*(j >> 8))*KEEP + (j & 255);
  int t = threadIdx.x;
  int node = perm[row];
  float gt = gate[row];
  float4 v = ((const float4*)(H + (size_t)node*D))[t];
  v.x *= gt; v.y *= gt; v.z *= gt; v.w *= gt;
  ((float4*)(out + (size_t)row*D))[t] = v;
}

__global__ __launch_bounds__(256) void gout_kernel(const float* __restrict__ H,
    const int* __restrict__ perm, const float* __restrict__ gate, float* __restrict__ out)
{
  __shared__ int sp[KEEP];
  __shared__ float sg[KEEP];
  int g = blockIdx.x, t = threadIdx.x;
  sp[t] = perm[g*KEEP + t];
  sg[t] = gate[g*KEEP + t];
  __syncthreads();
  int d0 = t, d1 = t + 256;
  float mx0 = -INFINITY, mx1 = -INFINITY;
  float s0 = 0.f, s1 = 0.f;
  for (int rI=0; rI<KEEP; rI++){
    const float* hr = H + (size_t)sp[rI]*D;
    float gt = sg[rI];
    float v0 = hr[d0]*gt, v1 = hr[d1]*gt;
    mx0 = fmaxf(mx0, v0); mx1 = fmaxf(mx1, v1);
    s0 += v0; s1 += v1;
  }
  float* go = out + (size_t)g*1024;
  go[d0] = mx0; go[d1] = mx1;
  go[512+d0] = s0; go[512+d1] = s1;
}

// ---------------- launch ----------------

extern "C" void kernel_launch(void* const* d_in, const int* in_sizes, int n_in,
                              void* d_out, int out_size, void* d_ws, size_t ws_size,
                              hipStream_t stream)
{
  (void)in_sizes; (void)n_in; (void)out_size; (void)ws_size;
  const void* x   = d_in[0];
  const int* src  = (const int*)d_in[1];
  const int* dst  = (const int*)d_in[2];
  const void* W1  = d_in[3];
  const void* b1  = d_in[4];
  const void* W2  = d_in[5];
  const void* b2  = d_in[6];
  const void* sW1 = d_in[7];
  const void* sb1 = d_in[8];
  const void* sW2 = d_in[9];
  const void* sb2 = d_in[10];
  float* out = (float*)d_out;

  char* ws = (char*)d_ws;
  size_t off = 0;
  auto alloc = [&](size_t bytes){ void* p = ws + off; off += (bytes + 255) & ~(size_t)255; return p; };
  int*   flags  = (int*)  alloc(2*4);
  int*   dego   = (int*)  alloc((size_t)NN*4);     // dego, degi, cursor contiguous
  int*   degi   = (int*)  alloc((size_t)NN*4);
  int*   cursor = (int*)  alloc((size_t)NN*4);
  float* no     = (float*)alloc((size_t)NN*4);
  float* ni     = (float*)alloc((size_t)NN*4);
  int*   rowp   = (int*)  alloc((size_t)(NN+1)*4);
  float* t1     = (float*)alloc((size_t)NN*4);
  float* t2     = (float*)alloc((size_t)NN*4);
  float* score  = (float*)alloc((size_t)NN*4);
  int*   perm   = (int*)  alloc((size_t)NB*KEEP*4);
  float* gate   = (float*)alloc((size_t)NB*KEEP*4);
  float* b1c    = (float*)alloc((size_t)D*4);
  float* b2c    = (float*)alloc((size_t)D*4);
  float* sW1c   = (float*)alloc((size_t)D*4);
  float* sW2c   = (float*)alloc((size_t)D*4);
  float* sbc    = (float*)alloc(2*4);
  u16*   W1Th   = (u16*)  alloc((size_t)D*D*2);
  u16*   W1Tl   = (u16*)  alloc((size_t)D*D*2);
  u16*   W2Th   = (u16*)  alloc((size_t)D*D*2);
  u16*   W2Tl   = (u16*)  alloc((size_t)D*D*2);
  int*   csr    = (int*)  alloc((size_t)EDGES*4);
  u16*   Hh     = (u16*)  alloc((size_t)NN*D*2);
  u16*   Hl     = (u16*)  alloc((size_t)NN*D*2);
  float* Y      = (float*)alloc((size_t)NN*D*4);
  float* H      = (float*)alloc((size_t)NN*D*4);
  // Xh/Xl live in H's space (dead until agg mode-1 writes H)
  u16*   Xh     = (u16*)H;
  u16*   Xl     = Xh + (size_t)NN*D;

  zero3_kernel<<<(3*NN)/256, 256, 0, stream>>>(dego);
  detect_kernel<<<1, 256, 0, stream>>>((const u16*)x, flags);
  deg_kernel <<<EDGES/256, 256, 0, stream>>>(src, dst, dego, degi);
  norm_kernel<<<NN/256,    256, 0, stream>>>(dego, degi, no, ni);
  scan_kernel<<<1,        1024, 0, stream>>>(degi, rowp);
  fill_kernel<<<EDGES/256, 256, 0, stream>>>(src, dst, rowp, cursor, csr);
  bcvt_kernel<<<1, 512, 0, stream>>>(flags, b1, b2, sW1, sW2, sb1, sb2, b1c, b2c, sW1c, sW2c, sbc);
  tsplit_kernel<<<dim3(16,16), dim3(32,8), 0, stream>>>(flags, W1, W1Th, W1Tl);
  tsplit_kernel<<<dim3(16,16), dim3(32,8), 0, stream>>>(flags, W2, W2Th, W2Tl);
  xsplit_kernel<<<(NN*D/4)/256, 256, 0, stream>>>(x, flags, Xh, Xl);

  // conv1: Y = (x @ W1) * no ; h1 = relu(agg) -> split bf16 (Hh, Hl)
  gemm_async<<<1024, 256, 0, stream>>>(Xh, Xl, W1Th, W1Tl, Y, no);
  agg_kernel<<<NN/2, 256, 0, stream>>>(Y, rowp, csr, ni, b1c, nullptr, Hh, Hl,
                                       nullptr, nullptr, nullptr, nullptr, 0);
  // conv2: Y = (h1 @ W2) * no ; h2 = relu(agg) -> f32 H + fused score dots
  gemm_async<<<1024, 256, 0, stream>>>(Hh, Hl, W2Th, W2Tl, Y, no);
  agg_kernel<<<NN/2, 256, 0, stream>>>(Y, rowp, csr, ni, b2c, H, nullptr, nullptr,
                                       sW1c, sW2c, t1, t2, 1);

  sagg_kernel<<<NN/256, 256, 0, stream>>>(t1, t2, rowp, csr, no, ni, sbc, score);
  topk_kernel<<<NB,     256, 0, stream>>>(score, perm, gate);

  pooled_kernel<<<NB*KEEP, 128, 0, stream>>>(H, perm, gate, out);
  gout_kernel  <<<NB,      256, 0, stream>>>(H, perm, gate, out + (size_t)NB*KEEP*D);
}

// Round 7
// 378.512 us; speedup vs baseline: 1.1181x; 1.1181x over previous
//
#include <hip/hip_runtime.h>
#include <math.h>

typedef unsigned short u16;
typedef __attribute__((ext_vector_type(8))) short bf16x8;
typedef __attribute__((ext_vector_type(4))) float f32x4;

#define NN 32768      // total nodes
#define EDGES 524288  // total edges
#define NB 64         // graphs
#define NPG 512       // nodes per graph
#define KEEP 256      // kept per graph
#define D 512         // feature dim

__device__ __forceinline__ float b2f(u16 h){ return __uint_as_float(((unsigned)h)<<16); }
__device__ __forceinline__ u16 f2b(float f){
  unsigned u = __float_as_uint(f);
  unsigned r = u + 0x7FFFu + ((u>>16)&1u);   // RNE
  return (u16)(r>>16);
}

// async global->LDS, 16B per lane (dest must be wave-uniform base + lane*16)
__device__ __forceinline__ void gload16(const void* g, void* l){
  __builtin_amdgcn_global_load_lds((const __attribute__((address_space(1))) void*)g,
                                   (__attribute__((address_space(3))) void*)l, 16, 0, 0);
}

// ---------- dtype detection: are float inputs f32 (flag=1) or bf16 (flag=0)? ----------
__global__ __launch_bounds__(256) void detect_kernel(const u16* __restrict__ xb, int* __restrict__ flags){
  __shared__ int cnt;
  if (threadIdx.x==0) cnt = 0;
  __syncthreads();
  u16 v = xb[threadIdx.x];
  int e = (v>>7)&0xFF;
  if (e > 140) atomicAdd(&cnt, 1);
  __syncthreads();
  if (threadIdx.x==0){ flags[0] = (cnt > 8) ? 1 : 0; flags[1] = 1; }
}

__global__ __launch_bounds__(256) void zero3_kernel(int* __restrict__ p){
  p[blockIdx.x*256 + threadIdx.x] = 0;   // covers dego, degi, cursor (3*NN ints)
}

// ---------------- graph preprocessing ----------------

__global__ __launch_bounds__(256) void deg_kernel(const int* __restrict__ src, const int* __restrict__ dst,
                                                  int* __restrict__ dego, int* __restrict__ degi){
  int e = blockIdx.x*256 + threadIdx.x;
  if (e < EDGES){
    atomicAdd(&dego[src[e]], 1);
    atomicAdd(&degi[dst[e]], 1);
  }
}

__global__ __launch_bounds__(256) void norm_kernel(const int* __restrict__ dego, const int* __restrict__ degi,
                                                   float* __restrict__ no, float* __restrict__ ni){
  int v = blockIdx.x*256 + threadIdx.x;
  if (v < NN){
    int a = dego[v]; if (a < 1) a = 1;
    int b = degi[v]; if (b < 1) b = 1;
    no[v] = (float)(1.0/sqrt((double)a));
    ni[v] = (float)(1.0/sqrt((double)b));
  }
}

__global__ __launch_bounds__(1024) void scan_kernel(const int* __restrict__ degi, int* __restrict__ rowp){
  __shared__ int sums[1024];
  int t = threadIdx.x;
  int base = t*32;
  int loc[32];
  int s = 0;
  #pragma unroll
  for (int i=0;i<32;i++){ loc[i] = s; s += degi[base+i]; }
  sums[t] = s;
  __syncthreads();
  for (int off=1; off<1024; off<<=1){
    int v = (t>=off) ? sums[t-off] : 0;
    __syncthreads();
    sums[t] += v;
    __syncthreads();
  }
  int excl = (t==0) ? 0 : sums[t-1];
  #pragma unroll
  for (int i=0;i<32;i++) rowp[base+i] = excl + loc[i];
  if (t==1023) rowp[NN] = sums[1023];
}

__global__ __launch_bounds__(256) void fill_kernel(const int* __restrict__ src, const int* __restrict__ dst,
                                                   const int* __restrict__ rowp, int* __restrict__ cursor,
                                                   int* __restrict__ csr){
  int e = blockIdx.x*256 + threadIdx.x;
  if (e < EDGES){
    int d = dst[e];
    int pos = atomicAdd(&cursor[d], 1);
    csr[rowp[d] + pos] = src[e];
  }
}

// ---------- small-tensor conversion to canonical f32 ----------
__global__ __launch_bounds__(512) void bcvt_kernel(const int* __restrict__ flags,
    const void* b1, const void* b2, const void* sW1, const void* sW2,
    const void* sb1, const void* sb2,
    float* b1c, float* b2c, float* sW1c, float* sW2c, float* sbc)
{
  int t = threadIdx.x;
  int f = flags[0];
  #define CV(p,i) (f ? ((const float*)(p))[i] : b2f(((const u16*)(p))[i]))
  b1c[t]  = CV(b1, t);
  b2c[t]  = CV(b2, t);
  sW1c[t] = CV(sW1, t);
  sW2c[t] = CV(sW2, t);
  if (t==0){ sbc[0] = CV(sb1,0); sbc[1] = CV(sb2,0); }
  #undef CV
}

// ---------- weight transpose + hi/lo bf16 split ----------
__global__ void tsplit_kernel(const int* __restrict__ flags, const void* __restrict__ W,
                              u16* __restrict__ WTh, u16* __restrict__ WTl){
  __shared__ float tile[32][33];
  int f = flags[0];
  int bx = blockIdx.x*32, by = blockIdx.y*32;
  int tx = threadIdx.x, ty = threadIdx.y; // (32,8)
  #pragma unroll
  for (int i=0;i<4;i++){
    size_t idx = (size_t)(by+ty+i*8)*D + bx+tx;
    tile[ty+i*8][tx] = f ? ((const float*)W)[idx] : b2f(((const u16*)W)[idx]);
  }
  __syncthreads();
  #pragma unroll
  for (int i=0;i<4;i++){
    float v = tile[tx][ty+i*8];
    u16 h = f2b(v);
    size_t o = (size_t)(bx+ty+i*8)*D + by+tx;
    WTh[o] = h;
    WTl[o] = f2b(v - b2f(h));
  }
}

// ---------- x split: f32 (or bf16) -> bf16 hi/lo ----------
__global__ __launch_bounds__(256) void xsplit_kernel(const void* __restrict__ X,
    const int* __restrict__ flags, u16* __restrict__ Xh, u16* __restrict__ Xl)
{
  size_t i = ((size_t)blockIdx.x*256 + threadIdx.x)*4;
  float v0,v1,v2,v3;
  if (flags[0]){
    float4 f = *(const float4*)((const float*)X + i);
    v0=f.x; v1=f.y; v2=f.z; v3=f.w;
  } else {
    ushort4 uv = *(const ushort4*)((const u16*)X + i);
    v0=b2f(uv.x); v1=b2f(uv.y); v2=b2f(uv.z); v3=b2f(uv.w);
  }
  ushort4 hh, hl;
  hh.x=f2b(v0); hl.x=f2b(v0-b2f(hh.x));
  hh.y=f2b(v1); hl.y=f2b(v1-b2f(hh.y));
  hh.z=f2b(v2); hl.z=f2b(v2-b2f(hh.z));
  hh.w=f2b(v3); hl.w=f2b(v3-b2f(hh.w));
  *(ushort4*)(Xh+i) = hh;
  *(ushort4*)(Xl+i) = hl;
}

// ---------------- GEMM: C = (A @ W) * rowscale; A,B pre-split bf16 hi/lo ----------------
// 256x256 tile, 8 waves (2M x 4N), BK=32, double-buffered LDS (128 KB),
// counted-drain schedule: STAGE(next) -> ds_read(cur) -> MFMA -> vmcnt(0) -> barrier.
// 96 MFMA / K-step / wave (hh + hl + lh products). Grid: 256 blocks = 1/CU.

__device__ __forceinline__ void gemm_tile256(int id, int& brow, int& bcol){
  int xcd = id & 7, k = id >> 3;           // k: 0..31
  brow = (xcd + 8*(k >> 1)) * 256;         // both bcol-blocks of a panel -> same XCD
  bcol = (k & 1) * 256;
}

__global__ __launch_bounds__(512, 2) void gemm256(
    const u16* __restrict__ Ahg, const u16* __restrict__ Alg,
    const u16* __restrict__ BTh, const u16* __restrict__ BTl,
    float* __restrict__ C, const float* __restrict__ rowscale)
{
  // [buf][arr: 0=Ah 1=Al 2=Bh 3=Bl][chunk c = q*256+row][8 u16]  (128 KB total)
  __shared__ alignas(16) u16 lds[2][4][8192];
  int t = threadIdx.x;
  int brow, bcol;
  gemm_tile256(blockIdx.x, brow, bcol);
  int wid = t>>6, lane = t&63;
  int wr = wid>>2, wc = wid&3;             // wave grid 2 x 4, wave owns 128x64
  int q = lane>>4, r = lane&15;
  f32x4 acc[8][4] = {};

  // staging: thread covers chunks c0 = wid*128+lane and c1 = c0+64 of every array
  int c0 = wid*128 + lane, c1 = c0 + 64;
  int q0 = c0>>8, r0 = c0&255, q1 = c1>>8, r1 = c1&255;
  const u16* sA0h = Ahg + (size_t)(brow+r0)*D + q0*8;
  const u16* sA1h = Ahg + (size_t)(brow+r1)*D + q1*8;
  const u16* sA0l = Alg + (size_t)(brow+r0)*D + q0*8;
  const u16* sA1l = Alg + (size_t)(brow+r1)*D + q1*8;
  const u16* sB0h = BTh + (size_t)(bcol+r0)*D + q0*8;
  const u16* sB1h = BTh + (size_t)(bcol+r1)*D + q1*8;
  const u16* sB0l = BTl + (size_t)(bcol+r0)*D + q0*8;
  const u16* sB1l = BTl + (size_t)(bcol+r1)*D + q1*8;

  #define STAGEK(B, KT) { int ko = (KT)*32; \
    gload16(sA0h+ko, &lds[B][0][c0*8]); gload16(sA1h+ko, &lds[B][0][c1*8]); \
    gload16(sA0l+ko, &lds[B][1][c0*8]); gload16(sA1l+ko, &lds[B][1][c1*8]); \
    gload16(sB0h+ko, &lds[B][2][c0*8]); gload16(sB1h+ko, &lds[B][2][c1*8]); \
    gload16(sB0l+ko, &lds[B][3][c0*8]); gload16(sB1l+ko, &lds[B][3][c1*8]); }

  STAGEK(0, 0)
  asm volatile("s_waitcnt vmcnt(0)" ::: "memory");
  __syncthreads();
  int cur = 0;
  for (int kt=0; kt<16; kt++){
    if (kt < 15) STAGEK(cur^1, kt+1)
    bf16x8 fbh[4], fbl[4];
    #pragma unroll
    for (int n=0;n<4;n++){
      fbh[n] = *(const bf16x8*)(&lds[cur][2][(q*256 + wc*64 + n*16 + r)*8]);
      fbl[n] = *(const bf16x8*)(&lds[cur][3][(q*256 + wc*64 + n*16 + r)*8]);
    }
    __builtin_amdgcn_s_setprio(1);
    #pragma unroll
    for (int m=0;m<8;m++){
      bf16x8 fah = *(const bf16x8*)(&lds[cur][0][(q*256 + wr*128 + m*16 + r)*8]);
      bf16x8 fal = *(const bf16x8*)(&lds[cur][1][(q*256 + wr*128 + m*16 + r)*8]);
      #pragma unroll
      for (int n=0;n<4;n++){
        acc[m][n] = __builtin_amdgcn_mfma_f32_16x16x32_bf16(fah, fbh[n], acc[m][n], 0,0,0);
        acc[m][n] = __builtin_amdgcn_mfma_f32_16x16x32_bf16(fah, fbl[n], acc[m][n], 0,0,0);
        acc[m][n] = __builtin_amdgcn_mfma_f32_16x16x32_bf16(fal, fbh[n], acc[m][n], 0,0,0);
      }
    }
    __builtin_amdgcn_s_setprio(0);
    asm volatile("s_waitcnt vmcnt(0)" ::: "memory");
    __syncthreads();
    cur ^= 1;
  }
  #undef STAGEK

  #pragma unroll
  for (int m=0;m<8;m++){
    int rowb = brow + wr*128 + m*16 + q*4;
    #pragma unroll
    for (int n=0;n<4;n++){
      int col = bcol + wc*64 + n*16 + r;
      #pragma unroll
      for (int g=0; g<4; g++){
        int row = rowb + g;
        C[(size_t)row*D + col] = acc[m][n][g] * rowscale[row];
      }
    }
  }
}

// -------- edge aggregation: relu( (sum_{u in N(v)} Y[u]) * ni[v] + b ) --------
// 2 nodes/block, 128 threads/node. CSR row hoisted into lane registers, indices via
// shfl; gather unrolled x4 (4 independent L2 accesses in flight). XCD-pinned per graph.
// mode 0: write split bf16 hi/lo.  mode 1: write f32 H + fused score dots.

__global__ __launch_bounds__(256) void agg_kernel(
    const float* __restrict__ Y, const int* __restrict__ rowp,
    const int* __restrict__ csr, const float* __restrict__ ni,
    const float* __restrict__ bias, float* __restrict__ H,
    u16* __restrict__ Hh, u16* __restrict__ Hl,
    const float* __restrict__ sW1, const float* __restrict__ sW2,
    float* __restrict__ t1, float* __restrict__ t2, int mode)
{
  int i = blockIdx.x;
  int xcd = i & 7, j = i >> 3;              // j: 0..2047
  int half = threadIdx.x >> 7;              // node within pair
  int t = threadIdx.x & 127;                // float4 chunk
  int lane = threadIdx.x & 63;
  int v = (xcd + 8*(j >> 8))*NPG + ((j & 255)*2 + half);
  int rp0 = rowp[v], rp1 = rowp[v+1];
  const float4* Yv = (const float4*)Y;
  float4 a = {0.f,0.f,0.f,0.f};
  for (int eb = rp0; eb < rp1; eb += 64){
    int cnt = rp1 - eb; if (cnt > 64) cnt = 64;
    int idx = (lane < cnt) ? csr[eb + lane] : 0;
    int e = 0;
    for (; e+4 <= cnt; e += 4){
      int u0 = __shfl(idx, e),   u1 = __shfl(idx, e+1);
      int u2 = __shfl(idx, e+2), u3 = __shfl(idx, e+3);
      float4 y0 = Yv[(size_t)u0*128 + t];
      float4 y1 = Yv[(size_t)u1*128 + t];
      float4 y2 = Yv[(size_t)u2*128 + t];
      float4 y3 = Yv[(size_t)u3*128 + t];
      a.x += (y0.x + y1.x) + (y2.x + y3.x);
      a.y += (y0.y + y1.y) + (y2.y + y3.y);
      a.z += (y0.z + y1.z) + (y2.z + y3.z);
      a.w += (y0.w + y1.w) + (y2.w + y3.w);
    }
    for (; e < cnt; e++){
      int u = __shfl(idx, e);
      float4 y = Yv[(size_t)u*128 + t];
      a.x += y.x; a.y += y.y; a.z += y.z; a.w += y.w;
    }
  }
  float w = ni[v];
  float4 b4 = ((const float4*)bias)[t];
  float4 rr;
  rr.x = fmaxf(a.x*w + b4.x, 0.f);
  rr.y = fmaxf(a.y*w + b4.y, 0.f);
  rr.z = fmaxf(a.z*w + b4.z, 0.f);
  rr.w = fmaxf(a.w*w + b4.w, 0.f);

  if (mode == 0){
    ushort4 hh, hl;
    hh.x = f2b(rr.x); hl.x = f2b(rr.x - b2f(hh.x));
    hh.y = f2b(rr.y); hl.y = f2b(rr.y - b2f(hh.y));
    hh.z = f2b(rr.z); hl.z = f2b(rr.z - b2f(hh.z));
    hh.w = f2b(rr.w); hl.w = f2b(rr.w - b2f(hh.w));
    *(ushort4*)(Hh + (size_t)v*D + t*4) = hh;
    *(ushort4*)(Hl + (size_t)v*D + t*4) = hl;
  } else {
    ((float4*)H)[(size_t)v*128 + t] = rr;
    float4 w1 = ((const float4*)sW1)[t];
    float4 w2 = ((const float4*)sW2)[t];
    float p1 = rr.x*w1.x + rr.y*w1.y + rr.z*w1.z + rr.w*w1.w;
    float p2 = rr.x*w2.x + rr.y*w2.y + rr.z*w2.z + rr.w*w2.w;
    #pragma unroll
    for (int off=32; off>=1; off>>=1){
      p1 += __shfl_xor(p1, off);
      p2 += __shfl_xor(p2, off);
    }
    __shared__ float red1[4], red2[4];
    int wv = threadIdx.x>>6;
    if (lane==0){ red1[wv] = p1; red2[wv] = p2; }
    __syncthreads();
    if (t==0){
      t1[v] = red1[half*2] + red1[half*2+1];
      t2[v] = red2[half*2] + red2[half*2+1];
    }
  }
}

// -------- score aggregation --------

__global__ __launch_bounds__(256) void sagg_kernel(
    const float* __restrict__ t1, const float* __restrict__ t2,
    const int* __restrict__ rowp, const int* __restrict__ csr,
    const float* __restrict__ no, const float* __restrict__ ni,
    const float* __restrict__ sbc, float* __restrict__ score)
{
  int v = blockIdx.x*256 + threadIdx.x;
  if (v >= NN) return;
  double a1 = 0.0, a2 = 0.0;
  int rp1 = rowp[v+1];
  for (int e=rowp[v]; e<rp1; e++){
    int u = csr[e];
    double w = (double)no[u];
    a1 += (double)t1[u]*w;
    a2 += (double)t2[u]*w;
  }
  double wi = (double)ni[v];
  double s1 = a1*wi + (double)sbc[0];
  double s2 = a2*wi + (double)sbc[1];
  score[v] = (float)(0.5*(s1+s2));
}

// -------- per-graph stable top-K via bitonic sort of 512 (score desc, idx asc) --------

__global__ __launch_bounds__(256) void topk_kernel(const float* __restrict__ score,
    int* __restrict__ perm, float* __restrict__ gate)
{
  __shared__ unsigned long long key[NPG];
  int g = blockIdx.x, t = threadIdx.x;
  for (int i=t; i<NPG; i+=256){
    float s = score[g*NPG + i];
    unsigned u = __float_as_uint(s);
    u = (u & 0x80000000u) ? ~u : (u | 0x80000000u);
    unsigned kd = ~u;
    key[i] = ((unsigned long long)kd<<32) | (unsigned)i;
  }
  __syncthreads();
  for (int k=2; k<=NPG; k<<=1){
    for (int j=k>>1; j>0; j>>=1){
      for (int i=t; i<NPG; i+=256){
        int ixj = i ^ j;
        if (ixj > i){
          unsigned long long a = key[i], b = key[ixj];
          bool up = ((i & k) == 0);
          if ((a > b) == up){ key[i] = b; key[ixj] = a; }
        }
      }
      __syncthreads();
    }
  }
  if (t < KEEP){
    unsigned long long e = key[t];
    int idx = (int)(e & 0xFFFFFFFFull);
    int node = g*NPG + idx;
    perm[g*KEEP + t] = node;
    gate[g*KEEP + t] = tanhf(score[node]);
  }
}

// -------- gated gather + readout (f32 outputs) --------

__global__ __launch_bounds__(128) void pooled_kernel(const float* __restrict__ H,
    const int* __restrict__ perm, const float* __restrict__ gate, float* __restrict__ out)
{
  int i = blockIdx.x;
  int xcd = i & 7, j = i >> 3;
  int row = (xcd + 8*(j >> 8))*KEEP + (j & 255);
  int t = threadIdx.x;
  int node = perm[row];
  float gt = gate[row];
  float4 v = ((const float4*)(H + (size_t)node*D))[t];
  v.x *= gt; v.y *= gt; v.z *= gt; v.w *= gt;
  ((float4*)(out + (size_t)row*D))[t] = v;
}

__global__ __launch_bounds__(256) void gout_kernel(const float* __restrict__ H,
    const int* __restrict__ perm, const float* __restrict__ gate, float* __restrict__ out)
{
  __shared__ int sp[KEEP];
  __shared__ float sg[KEEP];
  int g = blockIdx.x, t = threadIdx.x;
  sp[t] = perm[g*KEEP + t];
  sg[t] = gate[g*KEEP + t];
  __syncthreads();
  int d0 = t, d1 = t + 256;
  float mx0 = -INFINITY, mx1 = -INFINITY;
  float s0 = 0.f, s1 = 0.f;
  for (int rI=0; rI<KEEP; rI++){
    const float* hr = H + (size_t)sp[rI]*D;
    float gt = sg[rI];
    float v0 = hr[d0]*gt, v1 = hr[d1]*gt;
    mx0 = fmaxf(mx0, v0); mx1 = fmaxf(mx1, v1);
    s0 += v0; s1 += v1;
  }
  float* go = out + (size_t)g*1024;
  go[d0] = mx0; go[d1] = mx1;
  go[512+d0] = s0; go[512+d1] = s1;
}

// ---------------- launch ----------------

extern "C" void kernel_launch(void* const* d_in, const int* in_sizes, int n_in,
                              void* d_out, int out_size, void* d_ws, size_t ws_size,
                              hipStream_t stream)
{
  (void)in_sizes; (void)n_in; (void)out_size; (void)ws_size;
  const void* x   = d_in[0];
  const int* src  = (const int*)d_in[1];
  const int* dst  = (const int*)d_in[2];
  const void* W1  = d_in[3];
  const void* b1  = d_in[4];
  const void* W2  = d_in[5];
  const void* b2  = d_in[6];
  const void* sW1 = d_in[7];
  const void* sb1 = d_in[8];
  const void* sW2 = d_in[9];
  const void* sb2 = d_in[10];
  float* out = (float*)d_out;

  char* ws = (char*)d_ws;
  size_t off = 0;
  auto alloc = [&](size_t bytes){ void* p = ws + off; off += (bytes + 255) & ~(size_t)255; return p; };
  int*   flags  = (int*)  alloc(2*4);
  int*   dego   = (int*)  alloc((size_t)NN*4);     // dego, degi, cursor contiguous
  int*   degi   = (int*)  alloc((size_t)NN*4);
  int*   cursor = (int*)  alloc((size_t)NN*4);
  float* no     = (float*)alloc((size_t)NN*4);
  float* ni     = (float*)alloc((size_t)NN*4);
  int*   rowp   = (int*)  alloc((size_t)(NN+1)*4);
  float* t1     = (float*)alloc((size_t)NN*4);
  float* t2     = (float*)alloc((size_t)NN*4);
  float* score  = (float*)alloc((size_t)NN*4);
  int*   perm   = (int*)  alloc((size_t)NB*KEEP*4);
  float* gate   = (float*)alloc((size_t)NB*KEEP*4);
  float* b1c    = (float*)alloc((size_t)D*4);
  float* b2c    = (float*)alloc((size_t)D*4);
  float* sW1c   = (float*)alloc((size_t)D*4);
  float* sW2c   = (float*)alloc((size_t)D*4);
  float* sbc    = (float*)alloc(2*4);
  u16*   W1Th   = (u16*)  alloc((size_t)D*D*2);
  u16*   W1Tl   = (u16*)  alloc((size_t)D*D*2);
  u16*   W2Th   = (u16*)  alloc((size_t)D*D*2);
  u16*   W2Tl   = (u16*)  alloc((size_t)D*D*2);
  int*   csr    = (int*)  alloc((size_t)EDGES*4);
  u16*   Hh     = (u16*)  alloc((size_t)NN*D*2);
  u16*   Hl     = (u16*)  alloc((size_t)NN*D*2);
  float* Y      = (float*)alloc((size_t)NN*D*4);
  float* H      = (float*)alloc((size_t)NN*D*4);
  // Xh/Xl live in H's space (dead until agg mode-1 writes H)
  u16*   Xh     = (u16*)H;
  u16*   Xl     = Xh + (size_t)NN*D;

  zero3_kernel<<<(3*NN)/256, 256, 0, stream>>>(dego);
  detect_kernel<<<1, 256, 0, stream>>>((const u16*)x, flags);
  deg_kernel <<<EDGES/256, 256, 0, stream>>>(src, dst, dego, degi);
  norm_kernel<<<NN/256,    256, 0, stream>>>(dego, degi, no, ni);
  scan_kernel<<<1,        1024, 0, stream>>>(degi, rowp);
  fill_kernel<<<EDGES/256, 256, 0, stream>>>(src, dst, rowp, cursor, csr);
  bcvt_kernel<<<1, 512, 0, stream>>>(flags, b1, b2, sW1, sW2, sb1, sb2, b1c, b2c, sW1c, sW2c, sbc);
  tsplit_kernel<<<dim3(16,16), dim3(32,8), 0, stream>>>(flags, W1, W1Th, W1Tl);
  tsplit_kernel<<<dim3(16,16), dim3(32,8), 0, stream>>>(flags, W2, W2Th, W2Tl);
  xsplit_kernel<<<(NN*D/4)/256, 256, 0, stream>>>(x, flags, Xh, Xl);

  // conv1: Y = (x @ W1) * no ; h1 = relu(agg) -> split bf16 (Hh, Hl)
  gemm256<<<256, 512, 0, stream>>>(Xh, Xl, W1Th, W1Tl, Y, no);
  agg_kernel<<<NN/2, 256, 0, stream>>>(Y, rowp, csr, ni, b1c, nullptr, Hh, Hl,
                                       nullptr, nullptr, nullptr, nullptr, 0);
  // conv2: Y = (h1 @ W2) * no ; h2 = relu(agg) -> f32 H + fused score dots
  gemm256<<<256, 512, 0, stream>>>(Hh, Hl, W2Th, W2Tl, Y, no);
  agg_kernel<<<NN/2, 256, 0, stream>>>(Y, rowp, csr, ni, b2c, H, nullptr, nullptr,
                                       sW1c, sW2c, t1, t2, 1);

  sagg_kernel<<<NN/256, 256, 0, stream>>>(t1, t2, rowp, csr, no, ni, sbc, score);
  topk_kernel<<<NB,     256, 0, stream>>>(score, perm, gate);

  pooled_kernel<<<NB*KEEP, 128, 0, stream>>>(H, perm, gate, out);
  gout_kernel  <<<NB,      256, 0, stream>>>(H, perm, gate, out + (size_t)NB*KEEP*D);
}